// Round 6
// baseline (245.766 us; speedup 1.0000x reference)
//
#include <hip/hip_runtime.h>
#include <hip/hip_bf16.h>

#define HID 512
#define OD  256
#define HP  513
#define GPS 516              /* padded gamma/beta row stride (floats, 16B-aligned) */
#define NBLK 1026            /* 131328 rows / 128 per block */
#define EPSV 1e-5f

typedef float f32x4 __attribute__((ext_vector_type(4)));
typedef short s16x8 __attribute__((ext_vector_type(8)));

#define GLDS16(g, l) __builtin_amdgcn_global_load_lds( \
    (const __attribute__((address_space(1))) void*)(g), \
    (__attribute__((address_space(3))) void*)(l), 16, 0, 0)
#define GLDS4(g, l) __builtin_amdgcn_global_load_lds( \
    (const __attribute__((address_space(1))) void*)(g), \
    (__attribute__((address_space(3))) void*)(l), 4, 0, 0)

static __device__ __forceinline__ unsigned short f2bf(float f) {
    union { float f; unsigned u; } x; x.f = f;
    unsigned r = x.u + 0x7FFFu + ((x.u >> 16) & 1u);   // RNE
    return (unsigned short)(r >> 16);
}
static __device__ __forceinline__ unsigned pkbf(float x, float y) {
    float2 t; t.x = x; t.y = y;
    __hip_bfloat162 h = __float22bfloat162_rn(t);
    union { __hip_bfloat162 h; unsigned u; } c; c.h = h;
    return c.u;
}

// ---------- prep: gp/bp padded copies, vhT (bf16 swizzled [128][512]), vh512, ahT
__global__ void prep_all(const float* __restrict__ a, const float* __restrict__ v,
                         const float* __restrict__ gamma, const float* __restrict__ beta,
                         float* __restrict__ gp, float* __restrict__ bp,
                         unsigned short* __restrict__ vhT, float* __restrict__ vh512,
                         float* __restrict__ ahT) {
    int b = blockIdx.x, t = threadIdx.x;
    if (b < HP) {
        int i = b;
        for (int j = t; j < GPS; j += 256) {
            float g = 0.f, bb = 0.f;
            if (j < HP) { g = gamma[(size_t)i * HP + j]; bb = beta[(size_t)i * HP + j]; }
            gp[(size_t)i * GPS + j] = g;
            bp[(size_t)i * GPS + j] = bb;
        }
    } else if (b < HP + 128) {
        int n = b - HP;
        unsigned sw = (unsigned)((n & 7) << 4);
        for (int j = t; j < 512; j += 256) {
            float val = (j == 0) ? 1.f : v[n * HID + j - 1];
            unsigned byte = (unsigned)n * 1024u + (unsigned)((j >> 6) * 128)
                          + (((unsigned)((j & 63) * 2)) ^ sw);
            *(unsigned short*)((char*)vhT + byte) = f2bf(val);
        }
    } else if (b == HP + 128) {
        if (t < 128) vh512[t] = v[t * HID + 511];
    } else {
        int idx = (b - HP - 129) * 256 + t;
        if (idx < HP * 128) {
            int i = idx >> 7, m = idx & 127;
            ahT[idx] = (i == 0) ? 1.f : a[m * HID + i - 1];
        }
    }
}

// ---------- stats ------------------------------------------------------------
__global__ void stats_kernel(const float* __restrict__ a, const float* __restrict__ v,
                             float* __restrict__ mu, float* __restrict__ rsig) {
    __shared__ float s1[256], s2[256], s3[256], s4[256];
    int m = blockIdx.x, t = threadIdx.x;
    float a0 = a[m * HID + t], a1 = a[m * HID + t + 256];
    float v0 = v[m * HID + t], v1 = v[m * HID + t + 256];
    s1[t] = a0 + a1; s2[t] = a0 * a0 + a1 * a1;
    s3[t] = v0 + v1; s4[t] = v0 * v0 + v1 * v1;
    __syncthreads();
    for (int off = 128; off > 0; off >>= 1) {
        if (t < off) { s1[t] += s1[t + off]; s2[t] += s2[t + off];
                       s3[t] += s3[t + off]; s4[t] += s4[t + off]; }
        __syncthreads();
    }
    if (t == 0) {
        float Sa = 1.f + s1[0], Qa = 1.f + s2[0];
        float Sv = 1.f + s3[0], Qv = 1.f + s4[0];
        float muv = Sa * Sv / (float)((float)HP * (float)HP);
        float var = Qa * Qv / (float)((float)HP * (float)HP) - muv * muv;
        mu[m]   = muv;
        rsig[m] = rsqrtf(var + EPSV);
    }
}

// ---------- fused stage: W f32 -> LDS (GLDS4, src-swizzled), gamma-scale+cvt
// in-reg, MFMA vs vhT; Sg/Sb folded; j=512 peeled; ah-fold epilogue -> Pblk.
__global__ __launch_bounds__(512, 4) void stage_fused(
        const float* __restrict__ W, const float* __restrict__ gp,
        const float* __restrict__ bp, const unsigned short* __restrict__ vhT,
        const float* __restrict__ vh512, const float* __restrict__ ahT,
        float* __restrict__ Pblk, float* __restrict__ SgPart, float* __restrict__ SbPart) {
    __shared__ __align__(16) char arena[49152 + 64];
    char* Bs = arena + 32768;                  // 16 KB bf16 B tile
    float* red = (float*)arena;                // epilogue [2*128][4] (reuse W tile)
    float* sgr = (float*)(arena + 49152);      // [2][4]
    float* sbr = (float*)(arena + 49152 + 32); // [2][4]

    const int tid = threadIdx.x, lane = tid & 63, w = tid >> 6;
    const int wm = w >> 1, wn = w & 1;
    const int lr = lane & 15, lg = lane >> 4;
    const int gr0 = blockIdx.x * 128;
    const unsigned ofirst = (unsigned)gr0 / 513u;
    const unsigned lo0 = ofirst * 513u;
    const unsigned osw = lo0 + 513u;

    // per-mt row constants
    unsigned rbase[2], swA[2];
    const float* gpb[2];
    const float* bpb[2];
    bool hiA[2];
#pragma unroll
    for (int mt = 0; mt < 2; ++mt) {
        int r = wm * 32 + mt * 16 + lr;
        rbase[mt] = (unsigned)r * 256u;
        swA[mt] = (unsigned)((r & 7) << 4);
        unsigned oi = (unsigned)gr0 + (unsigned)r;
        bool hi = oi >= osw;
        unsigned ii = oi - (hi ? osw : lo0);
        hiA[mt] = hi;
        gpb[mt] = gp + (size_t)ii * GPS;
        bpb[mt] = bp + (size_t)ii * GPS;
    }

    f32x4 acc[2][4];
#pragma unroll
    for (int mt = 0; mt < 2; ++mt)
#pragma unroll
        for (int nt = 0; nt < 4; ++nt) acc[mt][nt] = {0.f, 0.f, 0.f, 0.f};
    float sg0 = 0.f, sg1 = 0.f, sb0 = 0.f, sb1 = 0.f;

    const size_t wrow0 = (size_t)gr0 * 513u;

    for (int s = 0; s < 8; ++s) {
        // ---- stage W tile (f32, src-index swizzled so frag reads are conflict-free)
#pragma unroll
        for (int q = 0; q < 16; ++q) {
            int r = w * 16 + q;
            const float* gsrc = W + wrow0 + (size_t)r * 513u
                              + (unsigned)(s * 64) + (unsigned)(lane ^ ((r & 7) << 2));
            GLDS4(gsrc, arena + r * 256);
        }
        // ---- stage B tile (bf16, pre-swizzled in vhT)
#pragma unroll
        for (int c = 0; c < 2; ++c) {
            int flat = (w * 2 + c) * 64 + lane;
            GLDS16((const char*)vhT + (size_t)(flat >> 3) * 1024 + s * 128 + (flat & 7) * 16,
                   Bs + (w * 2 + c) * 1024);
        }
        __syncthreads();   // drains vmcnt -> tiles ready
        // ---- convert A-frags in registers (gamma scale + bf16), fold Sg/Sb
        s16x8 afr[2][2];
#pragma unroll
        for (int mt = 0; mt < 2; ++mt) {
#pragma unroll
            for (int ks = 0; ks < 2; ++ks) {
                const unsigned J0 = (unsigned)(ks * 32 + lg * 8);
                f32x4 w0 = *(const f32x4*)(arena + rbase[mt] + ((4u * J0) ^ swA[mt]));
                f32x4 w1 = *(const f32x4*)(arena + rbase[mt] + ((4u * J0 + 16u) ^ swA[mt]));
                const float* gpr = gpb[mt] + s * 64 + J0;
                f32x4 g0 = *(const f32x4*)gpr;
                f32x4 g1 = *(const f32x4*)(gpr + 4);
                float p0 = g0[0]*w0[0], p1 = g0[1]*w0[1], p2 = g0[2]*w0[2], p3 = g0[3]*w0[3];
                float p4 = g1[0]*w1[0], p5 = g1[1]*w1[1], p6 = g1[2]*w1[2], p7 = g1[3]*w1[3];
                union { s16x8 v; unsigned u[4]; } f;
                f.u[0] = pkbf(p0, p1); f.u[1] = pkbf(p2, p3);
                f.u[2] = pkbf(p4, p5); f.u[3] = pkbf(p6, p7);
                afr[mt][ks] = f.v;
                if (wn == 0) {
                    const float* bpr = bpb[mt] + s * 64 + J0;
                    f32x4 b0v = *(const f32x4*)bpr;
                    f32x4 b1v = *(const f32x4*)(bpr + 4);
                    float ssum = ((p0 + p1) + (p2 + p3)) + ((p4 + p5) + (p6 + p7));
                    float tsum = 0.f;
                    tsum = fmaf(b0v[0], w0[0], tsum); tsum = fmaf(b0v[1], w0[1], tsum);
                    tsum = fmaf(b0v[2], w0[2], tsum); tsum = fmaf(b0v[3], w0[3], tsum);
                    tsum = fmaf(b1v[0], w1[0], tsum); tsum = fmaf(b1v[1], w1[1], tsum);
                    tsum = fmaf(b1v[2], w1[2], tsum); tsum = fmaf(b1v[3], w1[3], tsum);
                    if (hiA[mt]) { sg1 += ssum; sb1 += tsum; }
                    else         { sg0 += ssum; sb0 += tsum; }
                }
            }
        }
        // ---- MFMA
#pragma unroll
        for (int ks = 0; ks < 2; ++ks) {
#pragma unroll
            for (int nt = 0; nt < 4; ++nt) {
                unsigned n = (unsigned)(wn * 64 + nt * 16 + lr);
                s16x8 bfr = *(const s16x8*)(Bs + n * 128u
                              + (((unsigned)(ks * 64 + lg * 16)) ^ ((n & 7u) << 4)));
                acc[0][nt] = __builtin_amdgcn_mfma_f32_16x16x32_bf16(afr[0][ks], bfr, acc[0][nt], 0, 0, 0);
                acc[1][nt] = __builtin_amdgcn_mfma_f32_16x16x32_bf16(afr[1][ks], bfr, acc[1][nt], 0, 0, 0);
            }
        }
        __syncthreads();   // all reads done before next stage overwrites
    }

    // ---- peel j=512 (rank-1), fold into acc + Sg/Sb -------------------------
    float c512[2][4];
    float psg0 = 0.f, psg1 = 0.f, psb0 = 0.f, psb1 = 0.f;
#pragma unroll
    for (int mt = 0; mt < 2; ++mt)
#pragma unroll
        for (int e = 0; e < 4; ++e) {
            unsigned oi = (unsigned)gr0 + (unsigned)(wm * 32 + mt * 16 + lg * 4 + e);
            bool hi = oi >= osw;
            unsigned ii = oi - (hi ? osw : lo0);
            float w5 = W[(size_t)oi * 513u + 512u];
            float g5 = gp[(size_t)ii * GPS + 512];
            float p = g5 * w5;
            c512[mt][e] = p;
            if (wn == 0 && lr == 0) {   // each of the wave's 32 rows counted once
                float b5 = bp[(size_t)ii * GPS + 512];
                float q = b5 * w5;
                if (hi) { psg1 += p; psb1 += q; } else { psg0 += p; psb0 += q; }
            }
        }
#pragma unroll
    for (int nt = 0; nt < 4; ++nt) {
        float vm = vh512[wn * 64 + nt * 16 + lr];
#pragma unroll
        for (int mt = 0; mt < 2; ++mt)
#pragma unroll
            for (int e = 0; e < 4; ++e)
                acc[mt][nt][e] = fmaf(c512[mt][e], vm, acc[mt][nt][e]);
    }
    if (wn == 0) { psg0 += sg0; psg1 += sg1; psb0 += sb0; psb1 += sb1; }

    // ---- epilogue: ah-weighted fold, slot-split by o ------------------------
    float ps0[4], ps1[4];
#pragma unroll
    for (int nt = 0; nt < 4; ++nt) { ps0[nt] = 0.f; ps1[nt] = 0.f; }
#pragma unroll
    for (int mt = 0; mt < 2; ++mt)
#pragma unroll
        for (int e = 0; e < 4; ++e) {
            unsigned oi = (unsigned)gr0 + (unsigned)(wm * 32 + mt * 16 + lg * 4 + e);
            bool hi = oi >= osw;
            unsigned ii = oi - (hi ? osw : lo0);
            const float* ahr = ahT + (size_t)ii * 128;
#pragma unroll
            for (int nt = 0; nt < 4; ++nt) {
                float val = acc[mt][nt][e] * ahr[wn * 64 + nt * 16 + lr];
                ps0[nt] += hi ? 0.f : val;
                ps1[nt] += hi ? val : 0.f;
            }
        }
#pragma unroll
    for (int nt = 0; nt < 4; ++nt) {
        float r0 = ps0[nt], r1 = ps1[nt];
        r0 += __shfl_xor(r0, 16); r0 += __shfl_xor(r0, 32);
        r1 += __shfl_xor(r1, 16); r1 += __shfl_xor(r1, 32);
        ps0[nt] = r0; ps1[nt] = r1;
    }
    if (lane < 16) {
#pragma unroll
        for (int nt = 0; nt < 4; ++nt) {
            int col = wn * 64 + nt * 16 + lr;
            red[(0 * 128 + col) * 4 + wm] = ps0[nt];
            red[(1 * 128 + col) * 4 + wm] = ps1[nt];
        }
    }
#pragma unroll
    for (int off = 1; off < 64; off <<= 1) {
        psg0 += __shfl_xor(psg0, off); psg1 += __shfl_xor(psg1, off);
        psb0 += __shfl_xor(psb0, off); psb1 += __shfl_xor(psb1, off);
    }
    if (wn == 0 && lane == 0) {
        sgr[0 * 4 + wm] = psg0; sgr[1 * 4 + wm] = psg1;
        sbr[0 * 4 + wm] = psb0; sbr[1 * 4 + wm] = psb1;
    }
    __syncthreads();
    if (tid < 256) {
        int sl = tid >> 7, col = tid & 127;
        const float* rp = red + (size_t)(sl * 128 + col) * 4;
        Pblk[((size_t)blockIdx.x * 2 + sl) * 128 + col] = rp[0] + rp[1] + rp[2] + rp[3];
    }
    if (tid < 2) {
        SgPart[blockIdx.x * 2 + tid] = sgr[tid * 4 + 0] + sgr[tid * 4 + 1] + sgr[tid * 4 + 2] + sgr[tid * 4 + 3];
        SbPart[blockIdx.x * 2 + tid] = sbr[tid * 4 + 0] + sbr[tid * 4 + 1] + sbr[tid * 4 + 2] + sbr[tid * 4 + 3];
    }
}

// ---------- finalize ---------------------------------------------------------
__global__ void finalize_kernel(const float* __restrict__ Pblk, const float* __restrict__ SgPart,
                                const float* __restrict__ SbPart, const float* __restrict__ mu,
                                const float* __restrict__ rsig, const float* __restrict__ bias,
                                float* __restrict__ out) {
    int o = blockIdx.x, m = threadIdx.x;   // 128 threads
    __shared__ float sSg, sSb;
    int b0 = (o * HP) >> 7;
    int b1 = (o * HP + HP - 1) >> 7;
    float P = 0.f, Sg = 0.f, Sb = 0.f;
    for (int b = b0; b <= b1; ++b) {
        unsigned of = ((unsigned)b * 128u) / 513u;
        int sl = o - (int)of;
        if (sl < 0 || sl > 1) continue;
        P += Pblk[((size_t)b * 2 + sl) * 128 + m];
        if (m == 0) { Sg += SgPart[b * 2 + sl]; Sb += SbPart[b * 2 + sl]; }
    }
    if (m == 0) { sSg = Sg; sSb = Sb; }
    __syncthreads();
    float x = rsig[m] * (P - mu[m] * sSg) + sSb + bias[o];
    out[m * OD + o] = fmaxf(x, 0.f);
}

extern "C" void kernel_launch(void* const* d_in, const int* in_sizes, int n_in,
                              void* d_out, int out_size, void* d_ws, size_t ws_size,
                              hipStream_t stream) {
    const float* a     = (const float*)d_in[0];
    const float* v     = (const float*)d_in[1];
    const float* gamma = (const float*)d_in[2];
    const float* beta  = (const float*)d_in[3];
    const float* W     = (const float*)d_in[4];
    const float* bias  = (const float*)d_in[5];
    float* out = (float*)d_out;

    float* cur = (float*)d_ws;
    float* mu     = cur; cur += 128;
    float* rsig   = cur; cur += 128;
    float* SgPart = cur; cur += NBLK * 2;               // 2052
    float* SbPart = cur; cur += NBLK * 2;               // 2052
    float* Pblk   = cur; cur += (size_t)NBLK * 2 * 128; // 262656
    float* ahT    = cur; cur += (size_t)HP * 128;       // 65664
    float* vh512  = cur; cur += 128;
    float* gp     = cur; cur += (size_t)HP * GPS;       // 264708
    float* bp     = cur; cur += (size_t)HP * GPS;       // 264708
    unsigned short* vhT = (unsigned short*)cur;         // 128*512 bf16 = 128 KB

    prep_all<<<HP + 128 + 1 + 257, 256, 0, stream>>>(a, v, gamma, beta, gp, bp, vhT, vh512, ahT);
    stats_kernel<<<128, 256, 0, stream>>>(a, v, mu, rsig);
    stage_fused<<<NBLK, 512, 0, stream>>>(W, gp, bp, vhT, vh512, ahT, Pblk, SgPart, SbPart);
    finalize_kernel<<<OD, 128, 0, stream>>>(Pblk, SgPart, SbPart, mu, rsig, bias, out);
}

// Round 7
// 136.942 us; speedup vs baseline: 1.7947x; 1.7947x over previous
//
#include <hip/hip_runtime.h>
#include <hip/hip_bf16.h>

#define HID 512
#define OD  256
#define HP  513
#define KD  263169
#define NBLK 1026            /* 131328 rows / 128 per block */
#define EPSV 1e-5f

typedef float f32x4 __attribute__((ext_vector_type(4)));
typedef short s16x8 __attribute__((ext_vector_type(8)));

#define GLDS4(g, l) __builtin_amdgcn_global_load_lds( \
    (const __attribute__((address_space(1))) void*)(g), \
    (__attribute__((address_space(3))) void*)(l), 4, 0, 0)

static __device__ __forceinline__ unsigned short f2bf(float f) {
    union { float f; unsigned u; } x; x.f = f;
    unsigned r = x.u + 0x7FFFu + ((x.u >> 16) & 1u);   // RNE
    return (unsigned short)(r >> 16);
}
static __device__ __forceinline__ unsigned pkbf(float x, float y) {
    float2 t; t.x = x; t.y = y;
    __hip_bfloat162 h = __float22bfloat162_rn(t);
    union { __hip_bfloat162 h; unsigned u; } c; c.h = h;
    return c.u;
}

// ---------- prep: vhT plain [128][512] bf16, vh512, ahT ---------------------
__global__ void prep_all(const float* __restrict__ a, const float* __restrict__ v,
                         unsigned short* __restrict__ vhT, float* __restrict__ vh512,
                         float* __restrict__ ahT) {
    int b = blockIdx.x, t = threadIdx.x;
    if (b < 128) {
        int n = b;
        for (int k = t; k < 512; k += 256) {
            float val = (k == 0) ? 1.f : v[n * HID + k - 1];
            vhT[n * 512 + k] = f2bf(val);
        }
    } else if (b == 128) {
        if (t < 128) vh512[t] = v[t * HID + 511];
    } else {
        int idx = (b - 129) * 256 + t;
        if (idx < HP * 128) {
            int i = idx >> 7, m = idx & 127;
            ahT[idx] = (i == 0) ? 1.f : a[m * HID + i - 1];
        }
    }
}

// ---------- stats ------------------------------------------------------------
__global__ void stats_kernel(const float* __restrict__ a, const float* __restrict__ v,
                             float* __restrict__ mu, float* __restrict__ rsig) {
    __shared__ float s1[256], s2[256], s3[256], s4[256];
    int m = blockIdx.x, t = threadIdx.x;
    float a0 = a[m * HID + t], a1 = a[m * HID + t + 256];
    float v0 = v[m * HID + t], v1 = v[m * HID + t + 256];
    s1[t] = a0 + a1; s2[t] = a0 * a0 + a1 * a1;
    s3[t] = v0 + v1; s4[t] = v0 * v0 + v1 * v1;
    __syncthreads();
    for (int off = 128; off > 0; off >>= 1) {
        if (t < off) { s1[t] += s1[t + off]; s2[t] += s2[t + off];
                       s3[t] += s3[t + off]; s4[t] += s4[t + off]; }
        __syncthreads();
    }
    if (t == 0) {
        float Sa = 1.f + s1[0], Qa = 1.f + s2[0];
        float Sv = 1.f + s3[0], Qv = 1.f + s4[0];
        float muv = Sa * Sv / (float)((float)HP * (float)HP);
        float var = Qa * Qv / (float)((float)HP * (float)HP) - muv * muv;
        mu[m]   = muv;
        rsig[m] = rsqrtf(var + EPSV);
    }
}

// ---------- fused one-pass: sequential W stream, 16-row groups --------------
// Per group: stage 16 contiguous W rows (j<512) -> LDS f32 (stride 2048B);
// cooperative convert gamma*W -> bf16 A-tile in-place (stride 1040B, Sg/Sb
// folded coalesced); 16 MFMA/wave vs register B-frags; ah-fold -> psum.
__global__ __launch_bounds__(512, 4) void stage_fused(
        const float* __restrict__ W, const float* __restrict__ gamma,
        const float* __restrict__ beta, const unsigned short* __restrict__ vhT,
        const float* __restrict__ vh512, const float* __restrict__ ahT,
        float* __restrict__ Pblk, float* __restrict__ SgPart, float* __restrict__ SbPart) {
    __shared__ __align__(16) char lds[65536];
    char* const bufA = lds;
    char* const bufB = lds + 32768;

    const int tid = threadIdx.x, lane = tid & 63, w = tid >> 6;
    const int lr = lane & 15, lg = lane >> 4;
    const int b = blockIdx.x;
    const int gr0 = b * 128;
    const unsigned ofirst = (unsigned)gr0 / 513u;
    const unsigned lo0 = ofirst * 513u;
    const unsigned osw = lo0 + 513u;

    // B-frags register-resident (once per block, from L2-hot vhT)
    s16x8 bfr[16];
    {
        const unsigned short* vrow = vhT + (size_t)(w * 16 + lr) * 512 + lg * 8;
#pragma unroll
        for (int ks = 0; ks < 16; ++ks) bfr[ks] = *(const s16x8*)(vrow + ks * 32);
    }
    const float vhm = vh512[w * 16 + lr];
    const int m = w * 16 + lr;

    const int cr = tid >> 5;      // convert row 0..15
    const int cu = tid & 31;      // convert column-chunk

    float psum0 = 0.f, psum1 = 0.f;
    float sg0 = 0.f, sg1 = 0.f, sb0 = 0.f, sb1 = 0.f;

    auto STAGE = [&](char* dst, int g) {
        const float* base = W + (size_t)(gr0 + g * 16) * 513u;
#pragma unroll
        for (int rq = 0; rq < 2; ++rq) {
            const int rr = w * 2 + rq;
            const float* src = base + (size_t)rr * 513u + lane;
            char* d = dst + rr * 2048;
#pragma unroll
            for (int c = 0; c < 8; ++c)
                GLDS4(src + c * 64, d + c * 256);
        }
    };

    STAGE(bufA, 0);
    __syncthreads();

    for (int g = 0; g < 8; ++g) {
        char* cb = (g & 1) ? bufB : bufA;
        char* nb = (g & 1) ? bufA : bufB;
        if (g < 7) STAGE(nb, g + 1);

        // ---- convert read (coalesced) + gamma/beta + partial sums ----------
        unsigned oic = (unsigned)(gr0 + g * 16 + cr);
        bool chi = oic >= osw;
        unsigned iic = oic - (chi ? osw : lo0);
        const float* gbase = gamma + (size_t)iic * 513u + cu * 4;
        const float* bbase = beta  + (size_t)iic * 513u + cu * 4;
        const char* rb = cb + cr * 2048 + cu * 16;
        float pr[16]; float s = 0.f, t2 = 0.f;
#pragma unroll
        for (int q = 0; q < 4; ++q) {
            f32x4 wv = *(const f32x4*)(rb + q * 512);
#pragma unroll
            for (int i = 0; i < 4; ++i) {
                float gv = gbase[q * 128 + i];
                float bv = bbase[q * 128 + i];
                float p = gv * wv[i];
                pr[q * 4 + i] = p;
                s += p;
                t2 = fmaf(bv, wv[i], t2);
            }
        }
        if (chi) { sg1 += s; sb1 += t2; } else { sg0 += s; sb0 += t2; }
        __syncthreads();
        // ---- write A-tile bf16 in-place (front of cb) ----------------------
        {
            char* wb = cb + cr * 1040 + cu * 8;
#pragma unroll
            for (int q = 0; q < 4; ++q) {
                uint2 u2;
                u2.x = pkbf(pr[q * 4 + 0], pr[q * 4 + 1]);
                u2.y = pkbf(pr[q * 4 + 2], pr[q * 4 + 3]);
                *(uint2*)(wb + q * 256) = u2;
            }
        }
        __syncthreads();
        // ---- MFMA: 16 ks, B from registers ---------------------------------
        f32x4 acc = {0.f, 0.f, 0.f, 0.f};
        const char* ab = cb + lr * 1040 + lg * 16;
#pragma unroll
        for (int ks = 0; ks < 16; ++ks) {
            s16x8 afr = *(const s16x8*)(ab + ks * 64);
            acc = __builtin_amdgcn_mfma_f32_16x16x32_bf16(afr, bfr[ks], acc, 0, 0, 0);
        }
        // ---- ah-fold + j=512 peel ------------------------------------------
#pragma unroll
        for (int e = 0; e < 4; ++e) {
            unsigned oi = (unsigned)(gr0 + g * 16 + lg * 4 + e);
            bool hi = oi >= osw;
            unsigned ii = oi - (hi ? osw : lo0);
            float w5 = W[(size_t)oi * 513u + 512u];
            float g5 = gamma[(size_t)ii * 513u + 512u];
            float p512 = g5 * w5;
            float ah = ahT[(size_t)ii * 128u + m];
            float val = fmaf(p512, vhm, acc[e]) * ah;
            if (hi) psum1 += val; else psum0 += val;
            if (w == 0 && lr == 0) {
                float b5 = beta[(size_t)ii * 513u + 512u];
                float q5 = b5 * w5;
                if (hi) { sg1 += p512; sb1 += q5; } else { sg0 += p512; sb0 += q5; }
            }
        }
        __syncthreads();
    }

    // ---- epilogue -----------------------------------------------------------
    psum0 += __shfl_xor(psum0, 16); psum0 += __shfl_xor(psum0, 32);
    psum1 += __shfl_xor(psum1, 16); psum1 += __shfl_xor(psum1, 32);
    if (lane < 16) {
        Pblk[((size_t)b * 2 + 0) * 128 + m] = psum0;
        Pblk[((size_t)b * 2 + 1) * 128 + m] = psum1;
    }
#pragma unroll
    for (int off = 1; off < 64; off <<= 1) {
        sg0 += __shfl_xor(sg0, off); sg1 += __shfl_xor(sg1, off);
        sb0 += __shfl_xor(sb0, off); sb1 += __shfl_xor(sb1, off);
    }
    float* redS = (float*)lds;
    if (lane == 0) {
        redS[w] = sg0; redS[8 + w] = sg1; redS[16 + w] = sb0; redS[24 + w] = sb1;
    }
    __syncthreads();
    if (tid < 2) {
        float S = 0.f, T = 0.f;
#pragma unroll
        for (int k = 0; k < 8; ++k) { S += redS[tid * 8 + k]; T += redS[16 + tid * 8 + k]; }
        SgPart[b * 2 + tid] = S;
        SbPart[b * 2 + tid] = T;
    }
}

// ---------- finalize ---------------------------------------------------------
__global__ void finalize_kernel(const float* __restrict__ Pblk, const float* __restrict__ SgPart,
                                const float* __restrict__ SbPart, const float* __restrict__ mu,
                                const float* __restrict__ rsig, const float* __restrict__ bias,
                                float* __restrict__ out) {
    int o = blockIdx.x, m = threadIdx.x;   // 128 threads
    __shared__ float sSg, sSb;
    int b0 = (o * HP) >> 7;
    int b1 = (o * HP + HP - 1) >> 7;
    float P = 0.f, Sg = 0.f, Sb = 0.f;
    for (int b = b0; b <= b1; ++b) {
        unsigned of = ((unsigned)b * 128u) / 513u;
        int sl = o - (int)of;
        if (sl < 0 || sl > 1) continue;
        P += Pblk[((size_t)b * 2 + sl) * 128 + m];
        if (m == 0) { Sg += SgPart[b * 2 + sl]; Sb += SbPart[b * 2 + sl]; }
    }
    if (m == 0) { sSg = Sg; sSb = Sb; }
    __syncthreads();
    float x = rsig[m] * (P - mu[m] * sSg) + sSb + bias[o];
    out[m * OD + o] = fmaxf(x, 0.f);
}

extern "C" void kernel_launch(void* const* d_in, const int* in_sizes, int n_in,
                              void* d_out, int out_size, void* d_ws, size_t ws_size,
                              hipStream_t stream) {
    const float* a     = (const float*)d_in[0];
    const float* v     = (const float*)d_in[1];
    const float* gamma = (const float*)d_in[2];
    const float* beta  = (const float*)d_in[3];
    const float* W     = (const float*)d_in[4];
    const float* bias  = (const float*)d_in[5];
    float* out = (float*)d_out;

    float* cur = (float*)d_ws;
    float* mu     = cur; cur += 128;
    float* rsig   = cur; cur += 128;
    float* SgPart = cur; cur += NBLK * 2;               // 2052
    float* SbPart = cur; cur += NBLK * 2;               // 2052
    float* Pblk   = cur; cur += (size_t)NBLK * 2 * 128; // 262656
    float* ahT    = cur; cur += (size_t)HP * 128;       // 65664
    float* vh512  = cur; cur += 128;
    unsigned short* vhT = (unsigned short*)cur;         // 128*512 bf16 = 128 KB

    prep_all<<<128 + 1 + 257, 256, 0, stream>>>(a, v, vhT, vh512, ahT);
    stats_kernel<<<128, 256, 0, stream>>>(a, v, mu, rsig);
    stage_fused<<<NBLK, 512, 0, stream>>>(W, gamma, beta, vhT, vh512, ahT, Pblk, SgPart, SbPart);
    finalize_kernel<<<OD, 128, 0, stream>>>(Pblk, SgPart, SbPart, mu, rsig, bias, out);
}